// Round 1
// baseline (92.538 us; speedup 1.0000x reference)
//
#include <hip/hip_runtime.h>
#include <hip/hip_bf16.h>

// ContinuousCoprimality: per-row binary-quantized entropy interaction.
// B=4096 rows, F=16384 features. One block per row; three positive-counts
// in one pass; entropy epilogue on thread 0.

#define FEAT 16384
#define BLOCK 256
#define VEC_PER_THREAD (FEAT / 4 / BLOCK)  // 16 float4 per thread per input

__device__ __forceinline__ float entropy_from_count(int c1) {
    // Matches: probs = [c0,c1] / float32(16384 + 1e-8) == c/16384 exactly in f32.
    // terms = where(p>0, p*log2(p+1e-10), 0); H = -sum(terms)
    const float n = 16384.0f;
    float p1 = (float)c1 / n;
    float p0 = (float)(16384 - c1) / n;
    float t0 = (p0 > 0.0f) ? p0 * log2f(p0 + 1e-10f) : 0.0f;
    float t1 = (p1 > 0.0f) ? p1 * log2f(p1 + 1e-10f) : 0.0f;
    return -(t0 + t1);
}

__global__ void __launch_bounds__(BLOCK)
coprimality_kernel(const float* __restrict__ ri,
                   const float* __restrict__ rj,
                   float* __restrict__ out, int B) {
    const int row = blockIdx.x;
    const float4* __restrict__ pi =
        reinterpret_cast<const float4*>(ri + (size_t)row * FEAT);
    const float4* __restrict__ pj =
        reinterpret_cast<const float4*>(rj + (size_t)row * FEAT);

    int ci = 0, cj = 0, cij = 0;
#pragma unroll
    for (int k = 0; k < VEC_PER_THREAD; ++k) {
        const int idx = threadIdx.x + k * BLOCK;  // coalesced: lane-contiguous
        float4 a = pi[idx];
        float4 b = pj[idx];
        ci  += (a.x > 0.0f) + (a.y > 0.0f) + (a.z > 0.0f) + (a.w > 0.0f);
        cj  += (b.x > 0.0f) + (b.y > 0.0f) + (b.z > 0.0f) + (b.w > 0.0f);
        cij += (a.x + b.x > 0.0f) + (a.y + b.y > 0.0f) +
               (a.z + b.z > 0.0f) + (a.w + b.w > 0.0f);
    }

    // wave (64-lane) shuffle reduction
#pragma unroll
    for (int off = 32; off > 0; off >>= 1) {
        ci  += __shfl_down(ci, off);
        cj  += __shfl_down(cj, off);
        cij += __shfl_down(cij, off);
    }

    __shared__ int s[3][BLOCK / 64];
    const int lane = threadIdx.x & 63;
    const int wave = threadIdx.x >> 6;
    if (lane == 0) {
        s[0][wave] = ci;
        s[1][wave] = cj;
        s[2][wave] = cij;
    }
    __syncthreads();

    if (threadIdx.x == 0) {
        int Ci = 0, Cj = 0, Cij = 0;
#pragma unroll
        for (int w = 0; w < BLOCK / 64; ++w) {
            Ci  += s[0][w];
            Cj  += s[1][w];
            Cij += s[2][w];
        }
        float Hi  = entropy_from_count(Ci);
        float Hj  = entropy_from_count(Cj);
        float Hij = entropy_from_count(Cij);
        float E = (Hij - Hi) - Hj;  // left-assoc like the reference
        out[row]     = (E >= 0.0f) ? 1.0f : 0.0f;  // is_co_prime
        out[B + row] = E;
    }
}

extern "C" void kernel_launch(void* const* d_in, const int* in_sizes, int n_in,
                              void* d_out, int out_size, void* d_ws, size_t ws_size,
                              hipStream_t stream) {
    const float* ri = (const float*)d_in[0];
    const float* rj = (const float*)d_in[1];
    float* out = (float*)d_out;
    const int B = in_sizes[0] / FEAT;  // 4096

    coprimality_kernel<<<dim3(B), dim3(BLOCK), 0, stream>>>(ri, rj, out, B);
}

// Round 3
// 81.375 us; speedup vs baseline: 1.1372x; 1.1372x over previous
//
#include <hip/hip_runtime.h>
#include <hip/hip_bf16.h>

// ContinuousCoprimality: per-row binary-quantized entropy interaction.
// B=4096 rows, F=16384 features. One block per row; three positive-counts
// in one pass; entropy epilogue on thread 0.
// R3: non-temporal loads via clang ext_vector (HIP_vector_type rejected by
// the builtin) + batched loads (4 a's + 4 b's issued before compute).

#define FEAT 16384
#define BLOCK 256
#define VEC_PER_THREAD (FEAT / 4 / BLOCK)  // 16 float4 per thread per input
#define BATCH 4                            // float4s per stream per batch

typedef float f32x4 __attribute__((ext_vector_type(4)));

__device__ __forceinline__ float entropy_from_count(int c1) {
    // probs = [c0,c1] / float32(16384 + 1e-8) == c/16384 exactly in f32.
    // terms = where(p>0, p*log2(p+1e-10), 0); H = -sum(terms)
    const float n = 16384.0f;
    float p1 = (float)c1 / n;
    float p0 = (float)(16384 - c1) / n;
    float t0 = (p0 > 0.0f) ? p0 * log2f(p0 + 1e-10f) : 0.0f;
    float t1 = (p1 > 0.0f) ? p1 * log2f(p1 + 1e-10f) : 0.0f;
    return -(t0 + t1);
}

__global__ void __launch_bounds__(BLOCK)
coprimality_kernel(const float* __restrict__ ri,
                   const float* __restrict__ rj,
                   float* __restrict__ out, int B) {
    const int row = blockIdx.x;
    const f32x4* __restrict__ pi =
        reinterpret_cast<const f32x4*>(ri + (size_t)row * FEAT);
    const f32x4* __restrict__ pj =
        reinterpret_cast<const f32x4*>(rj + (size_t)row * FEAT);

    int ci = 0, cj = 0, cij = 0;
#pragma unroll
    for (int k = 0; k < VEC_PER_THREAD; k += BATCH) {
        f32x4 a[BATCH], b[BATCH];
        // Issue all 8 loads before touching any result -> 8 outstanding
        // vmem ops per wave per batch.
#pragma unroll
        for (int t = 0; t < BATCH; ++t) {
            const int idx = threadIdx.x + (k + t) * BLOCK;  // coalesced
            a[t] = __builtin_nontemporal_load(&pi[idx]);
            b[t] = __builtin_nontemporal_load(&pj[idx]);
        }
#pragma unroll
        for (int t = 0; t < BATCH; ++t) {
            ci  += (a[t].x > 0.0f) + (a[t].y > 0.0f) +
                   (a[t].z > 0.0f) + (a[t].w > 0.0f);
            cj  += (b[t].x > 0.0f) + (b[t].y > 0.0f) +
                   (b[t].z > 0.0f) + (b[t].w > 0.0f);
            cij += (a[t].x + b[t].x > 0.0f) + (a[t].y + b[t].y > 0.0f) +
                   (a[t].z + b[t].z > 0.0f) + (a[t].w + b[t].w > 0.0f);
        }
    }

    // wave (64-lane) shuffle reduction
#pragma unroll
    for (int off = 32; off > 0; off >>= 1) {
        ci  += __shfl_down(ci, off);
        cj  += __shfl_down(cj, off);
        cij += __shfl_down(cij, off);
    }

    __shared__ int s[3][BLOCK / 64];
    const int lane = threadIdx.x & 63;
    const int wave = threadIdx.x >> 6;
    if (lane == 0) {
        s[0][wave] = ci;
        s[1][wave] = cj;
        s[2][wave] = cij;
    }
    __syncthreads();

    if (threadIdx.x == 0) {
        int Ci = 0, Cj = 0, Cij = 0;
#pragma unroll
        for (int w = 0; w < BLOCK / 64; ++w) {
            Ci  += s[0][w];
            Cj  += s[1][w];
            Cij += s[2][w];
        }
        float Hi  = entropy_from_count(Ci);
        float Hj  = entropy_from_count(Cj);
        float Hij = entropy_from_count(Cij);
        float E = (Hij - Hi) - Hj;  // left-assoc like the reference
        out[row]     = (E >= 0.0f) ? 1.0f : 0.0f;  // is_co_prime
        out[B + row] = E;
    }
}

extern "C" void kernel_launch(void* const* d_in, const int* in_sizes, int n_in,
                              void* d_out, int out_size, void* d_ws, size_t ws_size,
                              hipStream_t stream) {
    const float* ri = (const float*)d_in[0];
    const float* rj = (const float*)d_in[1];
    float* out = (float*)d_out;
    const int B = in_sizes[0] / FEAT;  // 4096

    coprimality_kernel<<<dim3(B), dim3(BLOCK), 0, stream>>>(ri, rj, out, B);
}